// Round 10
// baseline (722.851 us; speedup 1.0000x reference)
//
#include <hip/hip_runtime.h>
#include <stdint.h>

#define AS1 __attribute__((address_space(1)))
#define AS3 __attribute__((address_space(3)))

typedef _Float16 f16x8 __attribute__((ext_vector_type(8)));
typedef float f32x4 __attribute__((ext_vector_type(4)));

__device__ __forceinline__ unsigned short f32_f16(float f) {
  union { _Float16 h; unsigned short u; } v; v.h = (_Float16)f; return v.u;
}
__device__ __forceinline__ float f16_f32(unsigned short u) {
  union { _Float16 h; unsigned short u; } v; v.u = u; return (float)v.h;
}
// plain staging (L1+L2 cached) — for the GEMM
__device__ __forceinline__ void gl_lds16(const unsigned short* g, unsigned short* l) {
  __builtin_amdgcn_global_load_lds((const AS1 unsigned int*)g, (AS3 unsigned int*)l, 16, 0, 0);
}
// coherent staging — bypass L1+L2, read the Infinity Cache (R6/R9-proven)
__device__ __forceinline__ void gl_lds16_coh(const unsigned short* g, unsigned short* l) {
  __builtin_amdgcn_global_load_lds((const AS1 unsigned int*)g, (AS3 unsigned int*)l, 16, 0, 17);
}
// L2-hit staging — bypass L1 only; valid when writer+readers share an XCD and
// sc1 stores update-in-place in L2 (hypothesis under test this round)
__device__ __forceinline__ void gl_lds16_l2(const unsigned short* g, unsigned short* l) {
  __builtin_amdgcn_global_load_lds((const AS1 unsigned int*)g, (AS3 unsigned int*)l, 16, 0, 1);
}
// sc0 scalar load: bypass L1, hit own-XCD L2
__device__ __forceinline__ unsigned ld_sc0(const unsigned* p) {
  unsigned v;
  asm volatile("global_load_dword %0, %1, off sc0\n\ts_waitcnt vmcnt(0)"
               : "=v"(v) : "v"(p) : "memory");
  return v;
}

// ---------------- fused f32 -> fp16 conversion (facts, Wr, W, mem_old) ----------
__global__ void cvt_all(const float4* __restrict__ sf, ushort4* __restrict__ df,
                        const float4* __restrict__ s1, ushort4* __restrict__ d1,
                        const float4* __restrict__ s2, ushort4* __restrict__ d2,
                        const float4* __restrict__ sm, ushort4* __restrict__ dm) {
  int i = blockIdx.x * blockDim.x + threadIdx.x;
  int st = gridDim.x * blockDim.x;
  for (int k = i; k < 4751360; k += st) {
    const float4* s; ushort4* d; int off;
    if (k < 4194304)      { s = sf; d = df; off = k; }
    else if (k < 4456448) { s = s1; d = d1; off = k - 4194304; }
    else if (k < 4718592) { s = s2; d = d2; off = k - 4456448; }
    else                  { s = sm; d = dm; off = k - 4718592; }
    float4 v = s[off];
    ushort4 o;
    o.x = f32_f16(v.x); o.y = f32_f16(v.y); o.z = f32_f16(v.z); o.w = f32_f16(v.w);
    d[off] = o;
  }
}

// ---------------- phase 1: C[t][b][0:2048] = facts(b,t,:) @ [Wr|W]^T (fp16 out) ----
// BK=64 (16 K-tiles), XOR source-swizzle staging. Epilogue packs 4 lanes'
// f16 via 2 DPP shfl_xor into one 8B uint2 store (R10: 4x fewer VMEM stores).
__global__ __launch_bounds__(256, 2) void gemm_fw(
    const unsigned short* __restrict__ A,
    const unsigned short* __restrict__ Bt,
    unsigned short* __restrict__ Ct)
{
  __shared__ __align__(16) unsigned short As[128 * 64];
  __shared__ __align__(16) unsigned short Bs[128 * 64];
  const int tid = threadIdx.x;
  const int lane = tid & 63;
  const int wv = tid >> 6;
  const int q = lane >> 4, ln = lane & 15;
  const int bm = blockIdx.x, bn = blockIdx.y;
  const int wm = (wv >> 1) * 64, wn = (wv & 1) * 64;

  f32x4 acc[4][4] = {};

  for (int kt = 0; kt < 1024; kt += 64) {
    __syncthreads();
#pragma unroll
    for (int rr = 0; rr < 4; ++rr) {
      int chunk = rr * 256 + tid;          // 0..1023
      int r = chunk >> 3, c = chunk & 7;   // 8 chunks (16B) per 128B row
      int cs = c ^ (r & 7);                // source chunk for this LDS pos
      gl_lds16(A + (size_t)(bm * 128 + r) * 1024 + kt + cs * 8, As + chunk * 8);
      gl_lds16(Bt + (size_t)(bn * 128 + r) * 1024 + kt + cs * 8, Bs + chunk * 8);
    }
    __syncthreads();
    f16x8 af[4][2], bfr[4][2];
#pragma unroll
    for (int mi = 0; mi < 4; ++mi)
#pragma unroll
      for (int kk = 0; kk < 2; ++kk)
        af[mi][kk] = *(const f16x8*)(As + (wm + mi * 16 + ln) * 64 + (((q + 4 * kk) ^ (ln & 7)) * 8));
#pragma unroll
    for (int ni = 0; ni < 4; ++ni)
#pragma unroll
      for (int kk = 0; kk < 2; ++kk)
        bfr[ni][kk] = *(const f16x8*)(Bs + (wn + ni * 16 + ln) * 64 + (((q + 4 * kk) ^ (ln & 7)) * 8));
#pragma unroll
    for (int kk = 0; kk < 2; ++kk)
#pragma unroll
      for (int mi = 0; mi < 4; ++mi)
#pragma unroll
        for (int ni = 0; ni < 4; ++ni)
          acc[mi][ni] = __builtin_amdgcn_mfma_f32_16x16x32_f16(af[mi][kk], bfr[ni][kk], acc[mi][ni], 0, 0, 0);
  }
#pragma unroll
  for (int mi = 0; mi < 4; ++mi)
#pragma unroll
    for (int ni = 0; ni < 4; ++ni)
#pragma unroll
      for (int r2 = 0; r2 < 4; ++r2) {
        int trow = wm + mi * 16 + q * 4 + r2;   // == t
        int col = bn * 128 + wn + ni * 16 + ln; // 0..2047: [fWr | fW]
        unsigned short hu = f32_f16(acc[mi][ni][r2]);
        unsigned short pu = (unsigned short)__shfl_xor((int)hu, 1, 64);
        unsigned v0 = (unsigned)hu | ((unsigned)pu << 16);       // cols ln, ln+1 (even ln)
        unsigned v1 = (unsigned)__shfl_xor((int)v0, 2, 64);      // cols ln+2, ln+3
        if (!(ln & 3)) {
          uint2 val; val.x = v0; val.y = v1;
          *(uint2*)(Ct + (size_t)trow * 262144 + (size_t)bm * 2048 + col) = val;
        }
      }
}

// ---------------- phase 2: the recurrence ----------------
// Grid 256 = 8 groups x 32 dim-slices; ga = blockIdx&7. Coherence v6:
// runtime XCD handshake (HW_REG_XCC_ID, published via proven IC atomics).
//  fast (group on one XCD): staging aux=1 (L2-hit), flag poll sc0 with
//    every-8th-iteration agent-load ESCAPE (cannot hang); h stores + flag
//    release stay sc1 agent atomics (proven) which write-through the shared
//    L2 (hypothesis: update-in-place).
//  fallback: exact R9 IC path (aux=17, agent-atomic polls).
__global__ __launch_bounds__(256, 2) void gru_recur(
    const unsigned short* __restrict__ fwx,   // [128 t][128 b][2048] f16
    const float* __restrict__ Urw, const float* __restrict__ Urb,
    const float* __restrict__ Uw,  const float* __restrict__ Ub,
    const float* __restrict__ g,              // [128 b][128 t]
    const float* __restrict__ mem_old,        // [128][1024]
    const int* __restrict__ nfp,              // [128]
    unsigned short* __restrict__ hbf,         // [2][128][1024] f16
    unsigned int* __restrict__ flg,           // [8 ga][32 blk][32 pad] u32
    unsigned int* __restrict__ xcc,           // [8 ga][32 blk][32 pad] u32
    float* __restrict__ out)                  // [128][1024] f32
{
  __shared__ __align__(16) unsigned char At[32768]; // 16 rows x 2048B, dense
  __shared__ float xchg[512];
  __shared__ int fast_lds;

  const int tid = threadIdx.x;
  const int lane = tid & 63;
  const int w = tid >> 6;
  const int q = lane >> 4;
  const int ln = lane & 15;
  const int matrix = w >> 1;
  const int ntile = w & 1;
  const int ga = blockIdx.x & 7;    // XCD-local group under round-robin dispatch
  const int dsl = blockIdx.x >> 3;  // dim-slice within group
  const int b0 = ga * 16;
  const int n_g = dsl * 32 + ntile * 16 + ln;

  // --- XCD-uniformity handshake (once, entirely over the proven IC path) ---
  unsigned my_xcc;
  asm("s_getreg_b32 %0, hwreg(HW_REG_XCC_ID)" : "=s"(my_xcc));
  if (tid == 0)
    __hip_atomic_store(&xcc[(ga * 32 + dsl) * 32], my_xcc + 1u,
                       __ATOMIC_RELAXED, __HIP_MEMORY_SCOPE_AGENT);
  if (w == 0) {
    unsigned* xp = &xcc[(ga * 32 + (lane & 31)) * 32];
    unsigned v;
    for (;;) {
      v = __hip_atomic_load(xp, __ATOMIC_RELAXED, __HIP_MEMORY_SCOPE_AGENT);
      if (__ballot(lane < 32 && v == 0u) == 0ull) break;
    }
    unsigned long long bad = __ballot(lane < 32 && v != my_xcc + 1u);
    if (lane == 0) fast_lds = (bad == 0ull);
  }

  // --- one-time: weights into registers (B-fragment layout: n=lane&15, k=q*8+j) ---
  const float* Wm = matrix ? Uw : Urw;
  f16x8 bw[32];
#pragma unroll
  for (int ks = 0; ks < 32; ++ks) {
    const float* s = Wm + (size_t)n_g * 1024 + ks * 32 + q * 8;
    float4 x0 = *(const float4*)s;
    float4 x1 = *(const float4*)(s + 4);
    f16x8 t;
    t[0] = (_Float16)x0.x; t[1] = (_Float16)x0.y;
    t[2] = (_Float16)x0.z; t[3] = (_Float16)x0.w;
    t[4] = (_Float16)x1.x; t[5] = (_Float16)x1.y;
    t[6] = (_Float16)x1.z; t[7] = (_Float16)x1.w;
    bw[ks] = t;
  }
  const float bias = (matrix ? Ub : Urb)[n_g];
  f32x4 acc = {bias, bias, bias, bias};

  float h_own[4] = {0.f, 0.f, 0.f, 0.f};
  int nf[4] = {0, 0, 0, 0};
  if (matrix == 0) {
#pragma unroll
    for (int r = 0; r < 4; ++r) {
      int b = b0 + q * 4 + r;
      h_own[r] = mem_old[(size_t)b * 1024 + n_g];
      nf[r] = nfp[b];
    }
  }

  __syncthreads();
  const int fast = fast_lds;

  // A-fragment read bases: row ln, chunk(ks) = (q + 4*ks) ^ (ln&7).
  const int swz = ln & 7;
  const int rowb = ln * 2048 + (q ^ (swz & 3)) * 16;
  const int be = rowb + ((swz >> 2) << 6);        // ks even
  const int bo = rowb + (((swz >> 2) ^ 1) << 6);  // ks odd

  for (int t = 0; t < 128; ++t) {
    // stage h(t) group tile (16 x 1024 f16 = 32KB)
    const unsigned short* hsrc = hbf + (size_t)(t & 1) * 131072 + (size_t)b0 * 1024;
    if (fast) {
#pragma unroll
      for (int j = 0; j < 8; ++j) {
        int blk = w * 8 + j;
        int m = blk >> 1, kh = blk & 1;
        gl_lds16_l2(hsrc + m * 1024 + kh * 512 + ((lane ^ (m & 7)) * 8),
                    (unsigned short*)(At + m * 2048 + kh * 1024));
      }
    } else {
#pragma unroll
      for (int j = 0; j < 8; ++j) {
        int blk = w * 8 + j;
        int m = blk >> 1, kh = blk & 1;
        gl_lds16_coh(hsrc + m * 1024 + kh * 512 + ((lane ^ (m & 7)) * 8),
                     (unsigned short*)(At + m * 2048 + kh * 1024));
      }
    }
    __syncthreads(); // drains vmcnt -> staging complete

    // epilogue operands: issue early, consumed after MFMA loop (plain cached loads)
    float fwrv[4], fwv[4], gv[4];
    if (matrix == 0) {
#pragma unroll
      for (int r = 0; r < 4; ++r) {
        int b = b0 + q * 4 + r;
        size_t base = (size_t)t * 262144 + (size_t)b * 2048;
        fwrv[r] = f16_f32(fwx[base + n_g]);
        fwv[r]  = f16_f32(fwx[base + 1024 + n_g]);
        gv[r]   = g[b * 128 + t];
      }
    }

#pragma unroll
    for (int ks = 0; ks < 32; ++ks) {
      const unsigned char* ap = At + (((ks & 1) ? bo : be) + ((ks >> 1) << 7));
      f16x8 a = *(const f16x8*)ap;
      acc = __builtin_amdgcn_mfma_f32_16x16x32_f16(a, bw[ks], acc, 0, 0, 0);
    }

    if (matrix == 1) { // u = U h + U_b -> exchange to r-side waves
#pragma unroll
      for (int r = 0; r < 4; ++r)
        xchg[ntile * 256 + (q * 4 + r) * 16 + ln] = acc[r];
    }
    __syncthreads();
    if (matrix == 0) {
      unsigned int* hb32 = (unsigned int*)(hbf + (size_t)((t + 1) & 1) * 131072);
#pragma unroll
      for (int r = 0; r < 4; ++r) {
        float u = xchg[ntile * 256 + (q * 4 + r) * 16 + ln];
        float rg = 1.0f / (1.0f + __expf(-(acc[r] + fwrv[r])));
        float pre = fwv[r] + rg * u;
        float e2 = __expf(-2.0f * fabsf(pre));
        float th = (1.0f - e2) / (1.0f + e2);
        float ht = copysignf(th, pre);
        float hn = gv[r] * ht + (1.0f - gv[r]) * h_own[r];
        h_own[r] = hn;
        int b = b0 + q * 4 + r;
        // pack adjacent dims (n_g even|odd) into u32, write-through (sc1)
        unsigned short hu = f32_f16(hn);
        unsigned short pu = (unsigned short)__shfl_xor((int)hu, 1, 64);
        if (!(ln & 1))
          __hip_atomic_store(&hb32[(b * 1024 + n_g) >> 1],
                             (unsigned)hu | ((unsigned)pu << 16),
                             __ATOMIC_RELAXED, __HIP_MEMORY_SCOPE_AGENT);
        if (t == nf[r] - 1) out[(size_t)b * 1024 + n_g] = hn;
      }
    }
    acc[0] = bias; acc[1] = bias; acc[2] = bias; acc[3] = bias;

    __syncthreads(); // vmcnt(0): h stores acked before flag release
    if (t < 127) {
      if (tid == 0)
        __hip_atomic_store(&flg[(ga * 32 + dsl) * 32], (unsigned)(t + 1),
                           __ATOMIC_RELAXED, __HIP_MEMORY_SCOPE_AGENT);
      if (w == 0) {
        unsigned int* fp = &flg[(ga * 32 + (lane & 31)) * 32];
        if (fast) {
          for (int it = 0;; ++it) {
            unsigned v = ((it & 7) == 7)
                ? __hip_atomic_load(fp, __ATOMIC_RELAXED, __HIP_MEMORY_SCOPE_AGENT)
                : ld_sc0(fp);
            if (__ballot(lane < 32 && v < (unsigned)(t + 1)) == 0ull) break;
          }
        } else {
          for (;;) {
            unsigned v = __hip_atomic_load(fp, __ATOMIC_RELAXED, __HIP_MEMORY_SCOPE_AGENT);
            if (__ballot(lane < 32 && v < (unsigned)(t + 1)) == 0ull) break;
          }
        }
      }
      __syncthreads();
    }
  }
}

extern "C" void kernel_launch(void* const* d_in, const int* in_sizes, int n_in,
                              void* d_out, int out_size, void* d_ws, size_t ws_size,
                              hipStream_t stream) {
  const float* facts     = (const float*)d_in[0]; // [128][128][1024]
  const int*   num_facts = (const int*)d_in[1];   // [128]
  const float* g         = (const float*)d_in[2]; // [128][128][1]
  const float* mem_old   = (const float*)d_in[3]; // [128][1][1024]
  const float* Wr        = (const float*)d_in[4]; // [1024][1024]
  const float* Urw       = (const float*)d_in[5];
  const float* Urb       = (const float*)d_in[6];
  const float* W         = (const float*)d_in[7];
  const float* Uw        = (const float*)d_in[8];
  const float* Ub        = (const float*)d_in[9];

  // workspace layout (f16 elements unless noted)
  unsigned short* facts_h = (unsigned short*)d_ws;        // 16,777,216
  unsigned short* wstack  = facts_h + 16777216;           //  2,097,152 ([Wr|W])
  unsigned short* fwx     = wstack + 2097152;             // 33,554,432 ([t][b][2048])
  unsigned short* hbf     = fwx + 33554432;               //    262,144 (2 x [128][1024])
  unsigned int*   flg     = (unsigned int*)(hbf + 262144);// 8*32*32 u32 = 32KB
  unsigned int*   xcc     = flg + 8192;                   // 8*32*32 u32 = 32KB
  float* out = (float*)d_out;

  hipMemsetAsync(flg, 0, 2 * 8 * 32 * 32 * 4, stream);    // flg + xcc
  cvt_all<<<4096, 256, 0, stream>>>(
      (const float4*)facts,   (ushort4*)facts_h,
      (const float4*)Wr,      (ushort4*)wstack,
      (const float4*)W,       (ushort4*)(wstack + 1048576),
      (const float4*)mem_old, (ushort4*)hbf);
  gemm_fw<<<dim3(128, 16), 256, 0, stream>>>(facts_h, wstack, fwx);
  gru_recur<<<256, 256, 0, stream>>>(fwx, Urw, Urb, Uw, Ub, g, mem_old, num_facts, hbf, flg, xcc, out);
}

// Round 11
// 658.815 us; speedup vs baseline: 1.0972x; 1.0972x over previous
//
#include <hip/hip_runtime.h>
#include <stdint.h>

#define AS1 __attribute__((address_space(1)))
#define AS3 __attribute__((address_space(3)))

typedef _Float16 f16x8 __attribute__((ext_vector_type(8)));
typedef float f32x4 __attribute__((ext_vector_type(4)));

__device__ __forceinline__ unsigned short f32_f16(float f) {
  union { _Float16 h; unsigned short u; } v; v.h = (_Float16)f; return v.u;
}
__device__ __forceinline__ float f16_f32(unsigned short u) {
  union { _Float16 h; unsigned short u; } v; v.u = u; return (float)v.h;
}
// plain staging (L1+L2 cached) — for the GEMM
__device__ __forceinline__ void gl_lds16(const unsigned short* g, unsigned short* l) {
  __builtin_amdgcn_global_load_lds((const AS1 unsigned int*)g, (AS3 unsigned int*)l, 16, 0, 0);
}
// coherent staging — bypass L1+L2, read the Infinity Cache (R6/R9-proven)
__device__ __forceinline__ void gl_lds16_coh(const unsigned short* g, unsigned short* l) {
  __builtin_amdgcn_global_load_lds((const AS1 unsigned int*)g, (AS3 unsigned int*)l, 16, 0, 17);
}

// ---------------- fused f32 -> fp16 conversion (facts, Wr, W, mem_old) ----------
__global__ void cvt_all(const float4* __restrict__ sf, ushort4* __restrict__ df,
                        const float4* __restrict__ s1, ushort4* __restrict__ d1,
                        const float4* __restrict__ s2, ushort4* __restrict__ d2,
                        const float4* __restrict__ sm, ushort4* __restrict__ dm) {
  int i = blockIdx.x * blockDim.x + threadIdx.x;
  int st = gridDim.x * blockDim.x;
  for (int k = i; k < 4751360; k += st) {
    const float4* s; ushort4* d; int off;
    if (k < 4194304)      { s = sf; d = df; off = k; }
    else if (k < 4456448) { s = s1; d = d1; off = k - 4194304; }
    else if (k < 4718592) { s = s2; d = d2; off = k - 4456448; }
    else                  { s = sm; d = dm; off = k - 4718592; }
    float4 v = s[off];
    ushort4 o;
    o.x = f32_f16(v.x); o.y = f32_f16(v.y); o.z = f32_f16(v.z); o.w = f32_f16(v.w);
    d[off] = o;
  }
}

// ---------------- phase 1: C[t][b][0:2048] = facts(b,t,:) @ [Wr|W]^T (fp16 out) ----
// BK=64 (16 K-tiles), XOR source-swizzle staging, scalar C-store (R10's packed
// epilogue regressed — reverted).
__global__ __launch_bounds__(256, 2) void gemm_fw(
    const unsigned short* __restrict__ A,
    const unsigned short* __restrict__ Bt,
    unsigned short* __restrict__ Ct)
{
  __shared__ __align__(16) unsigned short As[128 * 64];
  __shared__ __align__(16) unsigned short Bs[128 * 64];
  const int tid = threadIdx.x;
  const int lane = tid & 63;
  const int wv = tid >> 6;
  const int q = lane >> 4, ln = lane & 15;
  const int bm = blockIdx.x, bn = blockIdx.y;
  const int wm = (wv >> 1) * 64, wn = (wv & 1) * 64;

  f32x4 acc[4][4] = {};

  for (int kt = 0; kt < 1024; kt += 64) {
    __syncthreads();
#pragma unroll
    for (int rr = 0; rr < 4; ++rr) {
      int chunk = rr * 256 + tid;          // 0..1023
      int r = chunk >> 3, c = chunk & 7;   // 8 chunks (16B) per 128B row
      int cs = c ^ (r & 7);                // source chunk for this LDS pos
      gl_lds16(A + (size_t)(bm * 128 + r) * 1024 + kt + cs * 8, As + chunk * 8);
      gl_lds16(Bt + (size_t)(bn * 128 + r) * 1024 + kt + cs * 8, Bs + chunk * 8);
    }
    __syncthreads();
    f16x8 af[4][2], bfr[4][2];
#pragma unroll
    for (int mi = 0; mi < 4; ++mi)
#pragma unroll
      for (int kk = 0; kk < 2; ++kk)
        af[mi][kk] = *(const f16x8*)(As + (wm + mi * 16 + ln) * 64 + (((q + 4 * kk) ^ (ln & 7)) * 8));
#pragma unroll
    for (int ni = 0; ni < 4; ++ni)
#pragma unroll
      for (int kk = 0; kk < 2; ++kk)
        bfr[ni][kk] = *(const f16x8*)(Bs + (wn + ni * 16 + ln) * 64 + (((q + 4 * kk) ^ (ln & 7)) * 8));
#pragma unroll
    for (int kk = 0; kk < 2; ++kk)
#pragma unroll
      for (int mi = 0; mi < 4; ++mi)
#pragma unroll
        for (int ni = 0; ni < 4; ++ni)
          acc[mi][ni] = __builtin_amdgcn_mfma_f32_16x16x32_f16(af[mi][kk], bfr[ni][kk], acc[mi][ni], 0, 0, 0);
  }
#pragma unroll
  for (int mi = 0; mi < 4; ++mi)
#pragma unroll
    for (int ni = 0; ni < 4; ++ni)
#pragma unroll
      for (int r2 = 0; r2 < 4; ++r2) {
        int trow = wm + mi * 16 + q * 4 + r2;   // == t
        int col = bn * 128 + wn + ni * 16 + ln; // 0..2047: [fWr | fW]
        Ct[(size_t)trow * 262144 + (size_t)bm * 2048 + col] = f32_f16(acc[mi][ni][r2]);
      }
}

// ---------------- phase 2: the recurrence ----------------
// v7: 128 blocks x 512 threads (8 waves = 2 matrices x 4 ntiles, 64 dims each).
// 8 groups x 16 blocks (ga = blockIdx&7, XCD-locality heuristic). Halves the
// barrier degree (16 flags) and the h-staging IC amplification (16x32KB/group)
// vs R9's 32-block groups. Coherence semantics identical to R9 (proven): h via
// relaxed agent-atomic u32 write-through stores; staging aux=17 (IC); per-block
// flag lines 128B apart, tid0 release after full-block barrier, wave-0 lanes
// 0-31 poll (2 pollers/line).
__global__ __launch_bounds__(512, 2) void gru_recur(
    const unsigned short* __restrict__ fwx,   // [128 t][128 b][2048] f16
    const float* __restrict__ Urw, const float* __restrict__ Urb,
    const float* __restrict__ Uw,  const float* __restrict__ Ub,
    const float* __restrict__ g,              // [128 b][128 t]
    const float* __restrict__ mem_old,        // [128][1024]
    const int* __restrict__ nfp,              // [128]
    unsigned short* __restrict__ hbf,         // [2][128][1024] f16
    unsigned int* __restrict__ flg,           // [8 ga][16 blk][32 pad] u32
    float* __restrict__ out)                  // [128][1024] f32
{
  __shared__ __align__(16) unsigned char At[32768]; // 16 rows x 2048B, dense
  __shared__ float xchg[1024];

  const int tid = threadIdx.x;
  const int lane = tid & 63;
  const int w = tid >> 6;           // 0..7
  const int q = lane >> 4;
  const int ln = lane & 15;
  const int matrix = w >> 2;        // 0: Ur (r-gate), 1: U
  const int ntile = w & 3;          // 4 x 16 dims
  const int ga = blockIdx.x & 7;    // XCD-local group under round-robin dispatch
  const int dsl = blockIdx.x >> 3;  // dim-slice within group (0..15)
  const int b0 = ga * 16;
  const int n_g = dsl * 64 + ntile * 16 + ln;

  // --- one-time: weights into registers (B-fragment layout: n=lane&15, k=q*8+j) ---
  const float* Wm = matrix ? Uw : Urw;
  f16x8 bw[32];
#pragma unroll
  for (int ks = 0; ks < 32; ++ks) {
    const float* s = Wm + (size_t)n_g * 1024 + ks * 32 + q * 8;
    float4 x0 = *(const float4*)s;
    float4 x1 = *(const float4*)(s + 4);
    f16x8 t;
    t[0] = (_Float16)x0.x; t[1] = (_Float16)x0.y;
    t[2] = (_Float16)x0.z; t[3] = (_Float16)x0.w;
    t[4] = (_Float16)x1.x; t[5] = (_Float16)x1.y;
    t[6] = (_Float16)x1.z; t[7] = (_Float16)x1.w;
    bw[ks] = t;
  }
  const float bias = (matrix ? Ub : Urb)[n_g];
  f32x4 acc = {bias, bias, bias, bias};

  float h_own[4] = {0.f, 0.f, 0.f, 0.f};
  int nf[4] = {0, 0, 0, 0};
  if (matrix == 0) {
#pragma unroll
    for (int r = 0; r < 4; ++r) {
      int b = b0 + q * 4 + r;
      h_own[r] = mem_old[(size_t)b * 1024 + n_g];
      nf[r] = nfp[b];
    }
  }

  // A-fragment read bases: row ln, chunk(ks) = (q + 4*ks) ^ (ln&7).
  const int swz = ln & 7;
  const int rowb = ln * 2048 + (q ^ (swz & 3)) * 16;
  const int be = rowb + ((swz >> 2) << 6);        // ks even
  const int bo = rowb + (((swz >> 2) ^ 1) << 6);  // ks odd

  for (int t = 0; t < 128; ++t) {
    // stage h(t) group tile (16 x 1024 f16 = 32KB): 4 x 1KB chunks per wave
    const unsigned short* hsrc = hbf + (size_t)(t & 1) * 131072 + (size_t)b0 * 1024;
#pragma unroll
    for (int j = 0; j < 4; ++j) {
      int blk = w * 4 + j;              // 0..31
      int m = blk >> 1, kh = blk & 1;
      gl_lds16_coh(hsrc + m * 1024 + kh * 512 + ((lane ^ (m & 7)) * 8),
                   (unsigned short*)(At + m * 2048 + kh * 1024));
    }
    __syncthreads(); // B1: staging drained

    // epilogue operands: issue early, consumed after MFMA loop (plain cached loads)
    float fwrv[4], fwv[4], gv[4];
    if (matrix == 0) {
#pragma unroll
      for (int r = 0; r < 4; ++r) {
        int b = b0 + q * 4 + r;
        size_t base = (size_t)t * 262144 + (size_t)b * 2048;
        fwrv[r] = f16_f32(fwx[base + n_g]);
        fwv[r]  = f16_f32(fwx[base + 1024 + n_g]);
        gv[r]   = g[b * 128 + t];
      }
    }

#pragma unroll
    for (int ks = 0; ks < 32; ++ks) {
      const unsigned char* ap = At + (((ks & 1) ? bo : be) + ((ks >> 1) << 7));
      f16x8 a = *(const f16x8*)ap;
      acc = __builtin_amdgcn_mfma_f32_16x16x32_f16(a, bw[ks], acc, 0, 0, 0);
    }

    if (matrix == 1) { // u = U h + U_b -> exchange to r-side waves
#pragma unroll
      for (int r = 0; r < 4; ++r)
        xchg[ntile * 256 + (q * 4 + r) * 16 + ln] = acc[r];
    }
    __syncthreads(); // B2: xchg visible
    if (matrix == 0) {
      unsigned int* hb32 = (unsigned int*)(hbf + (size_t)((t + 1) & 1) * 131072);
#pragma unroll
      for (int r = 0; r < 4; ++r) {
        float u = xchg[ntile * 256 + (q * 4 + r) * 16 + ln];
        float rg = 1.0f / (1.0f + __expf(-(acc[r] + fwrv[r])));
        float pre = fwv[r] + rg * u;
        float e2 = __expf(-2.0f * fabsf(pre));
        float th = (1.0f - e2) / (1.0f + e2);
        float ht = copysignf(th, pre);
        float hn = gv[r] * ht + (1.0f - gv[r]) * h_own[r];
        h_own[r] = hn;
        int b = b0 + q * 4 + r;
        // pack adjacent dims (n_g even|odd) into u32, write-through to IC
        unsigned short hu = f32_f16(hn);
        unsigned short pu = (unsigned short)__shfl_xor((int)hu, 1, 64);
        if (!(ln & 1))
          __hip_atomic_store(&hb32[(b * 1024 + n_g) >> 1],
                             (unsigned)hu | ((unsigned)pu << 16),
                             __ATOMIC_RELAXED, __HIP_MEMORY_SCOPE_AGENT);
        if (t == nf[r] - 1) out[(size_t)b * 1024 + n_g] = hn;
      }
    }
    acc[0] = bias; acc[1] = bias; acc[2] = bias; acc[3] = bias;

    __syncthreads(); // B3: all waves' vmcnt drained -> h stores IC-acked
    if (t < 127) {
      if (tid == 0)
        __hip_atomic_store(&flg[(ga * 16 + dsl) * 32], (unsigned)(t + 1),
                           __ATOMIC_RELAXED, __HIP_MEMORY_SCOPE_AGENT);
      if (w == 0 && lane < 32) { // 2 pollers per flag line
        unsigned int* fp = &flg[(ga * 16 + (lane & 15)) * 32];
        for (;;) {
          unsigned v = __hip_atomic_load(fp, __ATOMIC_RELAXED, __HIP_MEMORY_SCOPE_AGENT);
          if (__ballot(v < (unsigned)(t + 1)) == 0ull) break;
        }
      }
      __syncthreads();
    }
  }
}

extern "C" void kernel_launch(void* const* d_in, const int* in_sizes, int n_in,
                              void* d_out, int out_size, void* d_ws, size_t ws_size,
                              hipStream_t stream) {
  const float* facts     = (const float*)d_in[0]; // [128][128][1024]
  const int*   num_facts = (const int*)d_in[1];   // [128]
  const float* g         = (const float*)d_in[2]; // [128][128][1]
  const float* mem_old   = (const float*)d_in[3]; // [128][1][1024]
  const float* Wr        = (const float*)d_in[4]; // [1024][1024]
  const float* Urw       = (const float*)d_in[5];
  const float* Urb       = (const float*)d_in[6];
  const float* W         = (const float*)d_in[7];
  const float* Uw        = (const float*)d_in[8];
  const float* Ub        = (const float*)d_in[9];

  // workspace layout (f16 elements unless noted)
  unsigned short* facts_h = (unsigned short*)d_ws;        // 16,777,216
  unsigned short* wstack  = facts_h + 16777216;           //  2,097,152 ([Wr|W])
  unsigned short* fwx     = wstack + 2097152;             // 33,554,432 ([t][b][2048])
  unsigned short* hbf     = fwx + 33554432;               //    262,144 (2 x [128][1024])
  unsigned int*   flg     = (unsigned int*)(hbf + 262144);// 8*16*32 u32 = 16KB
  float* out = (float*)d_out;

  hipMemsetAsync(flg, 0, 8 * 16 * 32 * 4, stream);
  cvt_all<<<4096, 256, 0, stream>>>(
      (const float4*)facts,   (ushort4*)facts_h,
      (const float4*)Wr,      (ushort4*)wstack,
      (const float4*)W,       (ushort4*)(wstack + 1048576),
      (const float4*)mem_old, (ushort4*)hbf);
  gemm_fw<<<dim3(128, 16), 256, 0, stream>>>(facts_h, wstack, fwx);
  gru_recur<<<128, 512, 0, stream>>>(fwx, Urw, Urb, Uw, Ub, g, mem_old, num_facts, hbf, flg, out);
}

// Round 12
// 622.499 us; speedup vs baseline: 1.1612x; 1.0583x over previous
//
#include <hip/hip_runtime.h>
#include <stdint.h>

#define AS1 __attribute__((address_space(1)))
#define AS3 __attribute__((address_space(3)))

typedef _Float16 f16x8 __attribute__((ext_vector_type(8)));
typedef float f32x4 __attribute__((ext_vector_type(4)));

__device__ __forceinline__ unsigned short f32_f16(float f) {
  union { _Float16 h; unsigned short u; } v; v.h = (_Float16)f; return v.u;
}
__device__ __forceinline__ float f16_f32(unsigned short u) {
  union { _Float16 h; unsigned short u; } v; v.u = u; return (float)v.h;
}
// plain staging (L1+L2 cached) — for the GEMM
__device__ __forceinline__ void gl_lds16(const unsigned short* g, unsigned short* l) {
  __builtin_amdgcn_global_load_lds((const AS1 unsigned int*)g, (AS3 unsigned int*)l, 16, 0, 0);
}
// coherent staging — bypass L1+L2, read the Infinity Cache (R6/R9-proven)
__device__ __forceinline__ void gl_lds16_coh(const unsigned short* g, unsigned short* l) {
  __builtin_amdgcn_global_load_lds((const AS1 unsigned int*)g, (AS3 unsigned int*)l, 16, 0, 17);
}
// L2 staging — bypass L1 only (fast path: reads own-XCD L2)
__device__ __forceinline__ void gl_lds16_l2(const unsigned short* g, unsigned short* l) {
  __builtin_amdgcn_global_load_lds((const AS1 unsigned int*)g, (AS3 unsigned int*)l, 16, 0, 1);
}
// sc0 scalar load: bypass L1, read own-XCD L2 (R10-proven instruction)
__device__ __forceinline__ unsigned ld_sc0(const unsigned* p) {
  unsigned v;
  asm volatile("global_load_dword %0, %1, off sc0\n\ts_waitcnt vmcnt(0)"
               : "=v"(v) : "v"(p) : "memory");
  return v;
}
// sc0 store: write through L1 to own-XCD L2, leave line valid there (under test)
__device__ __forceinline__ void st_sc0(unsigned* p, unsigned v) {
  asm volatile("global_store_dword %0, %1, off sc0" :: "v"(p), "v"(v) : "memory");
}

// ---------------- fused f32 -> fp16 conversion (facts, Wr, W, mem_old) ----------
__global__ void cvt_all(const float4* __restrict__ sf, ushort4* __restrict__ df,
                        const float4* __restrict__ s1, ushort4* __restrict__ d1,
                        const float4* __restrict__ s2, ushort4* __restrict__ d2,
                        const float4* __restrict__ sm, ushort4* __restrict__ dm) {
  int i = blockIdx.x * blockDim.x + threadIdx.x;
  int st = gridDim.x * blockDim.x;
  for (int k = i; k < 4751360; k += st) {
    const float4* s; ushort4* d; int off;
    if (k < 4194304)      { s = sf; d = df; off = k; }
    else if (k < 4456448) { s = s1; d = d1; off = k - 4194304; }
    else if (k < 4718592) { s = s2; d = d2; off = k - 4456448; }
    else                  { s = sm; d = dm; off = k - 4718592; }
    float4 v = s[off];
    ushort4 o;
    o.x = f32_f16(v.x); o.y = f32_f16(v.y); o.z = f32_f16(v.z); o.w = f32_f16(v.w);
    d[off] = o;
  }
}

// ---------------- phase 1: C[t][b][0:2048] = facts(b,t,:) @ [Wr|W]^T (fp16 out) ----
// BK=64 (16 K-tiles), XOR source-swizzle staging, scalar C-store (proven R9/R11).
__global__ __launch_bounds__(256, 2) void gemm_fw(
    const unsigned short* __restrict__ A,
    const unsigned short* __restrict__ Bt,
    unsigned short* __restrict__ Ct)
{
  __shared__ __align__(16) unsigned short As[128 * 64];
  __shared__ __align__(16) unsigned short Bs[128 * 64];
  const int tid = threadIdx.x;
  const int lane = tid & 63;
  const int wv = tid >> 6;
  const int q = lane >> 4, ln = lane & 15;
  const int bm = blockIdx.x, bn = blockIdx.y;
  const int wm = (wv >> 1) * 64, wn = (wv & 1) * 64;

  f32x4 acc[4][4] = {};

  for (int kt = 0; kt < 1024; kt += 64) {
    __syncthreads();
#pragma unroll
    for (int rr = 0; rr < 4; ++rr) {
      int chunk = rr * 256 + tid;          // 0..1023
      int r = chunk >> 3, c = chunk & 7;   // 8 chunks (16B) per 128B row
      int cs = c ^ (r & 7);                // source chunk for this LDS pos
      gl_lds16(A + (size_t)(bm * 128 + r) * 1024 + kt + cs * 8, As + chunk * 8);
      gl_lds16(Bt + (size_t)(bn * 128 + r) * 1024 + kt + cs * 8, Bs + chunk * 8);
    }
    __syncthreads();
    f16x8 af[4][2], bfr[4][2];
#pragma unroll
    for (int mi = 0; mi < 4; ++mi)
#pragma unroll
      for (int kk = 0; kk < 2; ++kk)
        af[mi][kk] = *(const f16x8*)(As + (wm + mi * 16 + ln) * 64 + (((q + 4 * kk) ^ (ln & 7)) * 8));
#pragma unroll
    for (int ni = 0; ni < 4; ++ni)
#pragma unroll
      for (int kk = 0; kk < 2; ++kk)
        bfr[ni][kk] = *(const f16x8*)(Bs + (wn + ni * 16 + ln) * 64 + (((q + 4 * kk) ^ (ln & 7)) * 8));
#pragma unroll
    for (int kk = 0; kk < 2; ++kk)
#pragma unroll
      for (int mi = 0; mi < 4; ++mi)
#pragma unroll
        for (int ni = 0; ni < 4; ++ni)
          acc[mi][ni] = __builtin_amdgcn_mfma_f32_16x16x32_f16(af[mi][kk], bfr[ni][kk], acc[mi][ni], 0, 0, 0);
  }
#pragma unroll
  for (int mi = 0; mi < 4; ++mi)
#pragma unroll
    for (int ni = 0; ni < 4; ++ni)
#pragma unroll
      for (int r2 = 0; r2 < 4; ++r2) {
        int trow = wm + mi * 16 + q * 4 + r2;   // == t
        int col = bn * 128 + wn + ni * 16 + ln; // 0..2047: [fWr | fW]
        Ct[(size_t)trow * 262144 + (size_t)bm * 2048 + col] = f32_f16(acc[mi][ni][r2]);
      }
}

// ---------------- phase 2: the recurrence (R9 shape + sc0-store fast path) ----
// Grid 256 = 8 groups x 32 dim-slices; ga = blockIdx&7. Coherence v8:
//  fast (XCD-uniform group, runtime-verified): h + flag stores sc0 (write
//    through to own-XCD L2, line stays valid), staging aux=1 (L2 read), polls
//    sc0 with every-8th agent escape. Liveness holds under EITHER sc0-store
//    semantics (L2-valid -> sc0 reads hit; IC-invalidate -> escape/miss sees IC).
//  fallback: R9 verbatim (IC atomics, aux=17).
__global__ __launch_bounds__(256, 2) void gru_recur(
    const unsigned short* __restrict__ fwx,   // [128 t][128 b][2048] f16
    const float* __restrict__ Urw, const float* __restrict__ Urb,
    const float* __restrict__ Uw,  const float* __restrict__ Ub,
    const float* __restrict__ g,              // [128 b][128 t]
    const float* __restrict__ mem_old,        // [128][1024]
    const int* __restrict__ nfp,              // [128]
    unsigned short* __restrict__ hbf,         // [2][128][1024] f16
    unsigned int* __restrict__ flg,           // [8 ga][32 blk][32 pad] u32
    unsigned int* __restrict__ xcc,           // [8 ga][32 blk][32 pad] u32
    float* __restrict__ out)                  // [128][1024] f32
{
  __shared__ __align__(16) unsigned char At[32768]; // 16 rows x 2048B, dense
  __shared__ float xchg[512];
  __shared__ int fast_lds;

  const int tid = threadIdx.x;
  const int lane = tid & 63;
  const int w = tid >> 6;
  const int q = lane >> 4;
  const int ln = lane & 15;
  const int matrix = w >> 1;
  const int ntile = w & 1;
  const int ga = blockIdx.x & 7;    // XCD-local group under round-robin dispatch
  const int dsl = blockIdx.x >> 3;  // dim-slice within group
  const int b0 = ga * 16;
  const int n_g = dsl * 32 + ntile * 16 + ln;

  // --- XCD-uniformity handshake (R10-proven, over the always-correct IC path) ---
  unsigned my_xcc;
  asm("s_getreg_b32 %0, hwreg(HW_REG_XCC_ID)" : "=s"(my_xcc));
  if (tid == 0)
    __hip_atomic_store(&xcc[(ga * 32 + dsl) * 32], my_xcc + 1u,
                       __ATOMIC_RELAXED, __HIP_MEMORY_SCOPE_AGENT);
  if (w == 0) {
    unsigned* xp = &xcc[(ga * 32 + (lane & 31)) * 32];
    unsigned v;
    for (;;) {
      v = __hip_atomic_load(xp, __ATOMIC_RELAXED, __HIP_MEMORY_SCOPE_AGENT);
      if (__ballot(lane < 32 && v == 0u) == 0ull) break;
    }
    unsigned long long bad = __ballot(lane < 32 && v != my_xcc + 1u);
    if (lane == 0) fast_lds = (bad == 0ull);
  }

  // --- one-time: weights into registers (B-fragment layout: n=lane&15, k=q*8+j) ---
  const float* Wm = matrix ? Uw : Urw;
  f16x8 bw[32];
#pragma unroll
  for (int ks = 0; ks < 32; ++ks) {
    const float* s = Wm + (size_t)n_g * 1024 + ks * 32 + q * 8;
    float4 x0 = *(const float4*)s;
    float4 x1 = *(const float4*)(s + 4);
    f16x8 t;
    t[0] = (_Float16)x0.x; t[1] = (_Float16)x0.y;
    t[2] = (_Float16)x0.z; t[3] = (_Float16)x0.w;
    t[4] = (_Float16)x1.x; t[5] = (_Float16)x1.y;
    t[6] = (_Float16)x1.z; t[7] = (_Float16)x1.w;
    bw[ks] = t;
  }
  const float bias = (matrix ? Ub : Urb)[n_g];
  f32x4 acc = {bias, bias, bias, bias};

  float h_own[4] = {0.f, 0.f, 0.f, 0.f};
  int nf[4] = {0, 0, 0, 0};
  if (matrix == 0) {
#pragma unroll
    for (int r = 0; r < 4; ++r) {
      int b = b0 + q * 4 + r;
      h_own[r] = mem_old[(size_t)b * 1024 + n_g];
      nf[r] = nfp[b];
    }
  }

  __syncthreads();
  const int fast = fast_lds;

  // A-fragment read bases: row ln, chunk(ks) = (q + 4*ks) ^ (ln&7).
  const int swz = ln & 7;
  const int rowb = ln * 2048 + (q ^ (swz & 3)) * 16;
  const int be = rowb + ((swz >> 2) << 6);        // ks even
  const int bo = rowb + (((swz >> 2) ^ 1) << 6);  // ks odd

  for (int t = 0; t < 128; ++t) {
    // stage h(t) group tile (16 x 1024 f16 = 32KB): 8 x 1KB chunks per wave
    const unsigned short* hsrc = hbf + (size_t)(t & 1) * 131072 + (size_t)b0 * 1024;
    if (fast) {
#pragma unroll
      for (int j = 0; j < 8; ++j) {
        int blk = w * 8 + j;
        int m = blk >> 1, kh = blk & 1;
        gl_lds16_l2(hsrc + m * 1024 + kh * 512 + ((lane ^ (m & 7)) * 8),
                    (unsigned short*)(At + m * 2048 + kh * 1024));
      }
    } else {
#pragma unroll
      for (int j = 0; j < 8; ++j) {
        int blk = w * 8 + j;
        int m = blk >> 1, kh = blk & 1;
        gl_lds16_coh(hsrc + m * 1024 + kh * 512 + ((lane ^ (m & 7)) * 8),
                     (unsigned short*)(At + m * 2048 + kh * 1024));
      }
    }
    __syncthreads(); // drains vmcnt -> staging complete

    // epilogue operands: issue early, consumed after MFMA loop (plain cached loads)
    float fwrv[4], fwv[4], gv[4];
    if (matrix == 0) {
#pragma unroll
      for (int r = 0; r < 4; ++r) {
        int b = b0 + q * 4 + r;
        size_t base = (size_t)t * 262144 + (size_t)b * 2048;
        fwrv[r] = f16_f32(fwx[base + n_g]);
        fwv[r]  = f16_f32(fwx[base + 1024 + n_g]);
        gv[r]   = g[b * 128 + t];
      }
    }

#pragma unroll
    for (int ks = 0; ks < 32; ++ks) {
      const unsigned char* ap = At + (((ks & 1) ? bo : be) + ((ks >> 1) << 7));
      f16x8 a = *(const f16x8*)ap;
      acc = __builtin_amdgcn_mfma_f32_16x16x32_f16(a, bw[ks], acc, 0, 0, 0);
    }

    if (matrix == 1) { // u = U h + U_b -> exchange to r-side waves
#pragma unroll
      for (int r = 0; r < 4; ++r)
        xchg[ntile * 256 + (q * 4 + r) * 16 + ln] = acc[r];
    }
    __syncthreads();
    if (matrix == 0) {
      unsigned int* hb32 = (unsigned int*)(hbf + (size_t)((t + 1) & 1) * 131072);
#pragma unroll
      for (int r = 0; r < 4; ++r) {
        float u = xchg[ntile * 256 + (q * 4 + r) * 16 + ln];
        float rg = 1.0f / (1.0f + __expf(-(acc[r] + fwrv[r])));
        float pre = fwv[r] + rg * u;
        float e2 = __expf(-2.0f * fabsf(pre));
        float th = (1.0f - e2) / (1.0f + e2);
        float ht = copysignf(th, pre);
        float hn = gv[r] * ht + (1.0f - gv[r]) * h_own[r];
        h_own[r] = hn;
        int b = b0 + q * 4 + r;
        // pack adjacent dims (n_g even|odd) into u32
        unsigned short hu = f32_f16(hn);
        unsigned short pu = (unsigned short)__shfl_xor((int)hu, 1, 64);
        if (!(ln & 1)) {
          unsigned val = (unsigned)hu | ((unsigned)pu << 16);
          unsigned* dst = &hb32[(b * 1024 + n_g) >> 1];
          if (fast) st_sc0(dst, val);                          // write-through to own-XCD L2
          else __hip_atomic_store(dst, val, __ATOMIC_RELAXED,  // write-through to IC
                                  __HIP_MEMORY_SCOPE_AGENT);
        }
        if (t == nf[r] - 1) out[(size_t)b * 1024 + n_g] = hn;
      }
    }
    acc[0] = bias; acc[1] = bias; acc[2] = bias; acc[3] = bias;

    __syncthreads(); // all waves' h stores drained (compiler vmcnt(0) + barrier)
    if (t < 127) {
      unsigned* myf = &flg[(ga * 32 + dsl) * 32];
      if (fast) {
        if (tid == 0) {
          asm volatile("s_waitcnt vmcnt(0)" ::: "memory"); // belt & braces
          st_sc0(myf, (unsigned)(t + 1));
        }
        if (w == 0) {
          unsigned int* fp = &flg[(ga * 32 + (lane & 31)) * 32];
          for (int it = 0;; ++it) {
            unsigned v = ((it & 7) == 7)
                ? __hip_atomic_load(fp, __ATOMIC_RELAXED, __HIP_MEMORY_SCOPE_AGENT)
                : ld_sc0(fp);
            if (__ballot(lane < 32 && v < (unsigned)(t + 1)) == 0ull) break;
          }
        }
      } else {
        if (tid == 0)
          __hip_atomic_store(myf, (unsigned)(t + 1),
                             __ATOMIC_RELAXED, __HIP_MEMORY_SCOPE_AGENT);
        if (w == 0) {
          unsigned int* fp = &flg[(ga * 32 + (lane & 31)) * 32];
          for (;;) {
            unsigned v = __hip_atomic_load(fp, __ATOMIC_RELAXED, __HIP_MEMORY_SCOPE_AGENT);
            if (__ballot(lane < 32 && v < (unsigned)(t + 1)) == 0ull) break;
          }
        }
      }
      __syncthreads();
    }
  }
}

extern "C" void kernel_launch(void* const* d_in, const int* in_sizes, int n_in,
                              void* d_out, int out_size, void* d_ws, size_t ws_size,
                              hipStream_t stream) {
  const float* facts     = (const float*)d_in[0]; // [128][128][1024]
  const int*   num_facts = (const int*)d_in[1];   // [128]
  const float* g         = (const float*)d_in[2]; // [128][128][1]
  const float* mem_old   = (const float*)d_in[3]; // [128][1][1024]
  const float* Wr        = (const float*)d_in[4]; // [1024][1024]
  const float* Urw       = (const float*)d_in[5];
  const float* Urb       = (const float*)d_in[6];
  const float* W         = (const float*)d_in[7];
  const float* Uw        = (const float*)d_in[8];
  const float* Ub        = (const float*)d_in[9];

  // workspace layout (f16 elements unless noted)
  unsigned short* facts_h = (unsigned short*)d_ws;        // 16,777,216
  unsigned short* wstack  = facts_h + 16777216;           //  2,097,152 ([Wr|W])
  unsigned short* fwx     = wstack + 2097152;             // 33,554,432 ([t][b][2048])
  unsigned short* hbf     = fwx + 33554432;               //    262,144 (2 x [128][1024])
  unsigned int*   flg     = (unsigned int*)(hbf + 262144);// 8*32*32 u32 = 32KB
  unsigned int*   xcc     = flg + 8192;                   // 8*32*32 u32 = 32KB
  float* out = (float*)d_out;

  hipMemsetAsync(flg, 0, 2 * 8 * 32 * 32 * 4, stream);    // flg + xcc
  cvt_all<<<4096, 256, 0, stream>>>(
      (const float4*)facts,   (ushort4*)facts_h,
      (const float4*)Wr,      (ushort4*)wstack,
      (const float4*)W,       (ushort4*)(wstack + 1048576),
      (const float4*)mem_old, (ushort4*)hbf);
  gemm_fw<<<dim3(128, 16), 256, 0, stream>>>(facts_h, wstack, fwx);
  gru_recur<<<256, 256, 0, stream>>>(fwx, Urw, Urb, Uw, Ub, g, mem_old, num_facts, hbf, flg, xcc, out);
}